// Round 1
// baseline (429.090 us; speedup 1.0000x reference)
//
#include <hip/hip_runtime.h>
#include <stdint.h>

// CondConceptSampler: single-query attention per (b,g) with GroupNorm'd q,k.
// Key algebra: GN(k) is affine per (b,g) -> sim[n] = rs * (w . x[:,n]) + const.
// Softmax drops const, so k is NEVER materialized. Only rs (variance of K over
// (s,n)) needs the full bilinear -> bf16 MFMA on transient K tiles.
//
// B=8 G=32 BW=64 S=64 CD=256 N=4096.  x: [8,2048,4096] fp32 (268 MB).

#define EPS 1e-5f
#define NN 4096
#define CHUNK 256
#define NCHUNK 16

typedef __bf16 bf16x8 __attribute__((ext_vector_type(8)));
typedef float f32x4 __attribute__((ext_vector_type(4)));
typedef short short8 __attribute__((ext_vector_type(8)));

__device__ __forceinline__ unsigned short f2bf(float f) {
  unsigned u = __builtin_bit_cast(unsigned, f);
  u += 0x7fffu + ((u >> 16) & 1u);   // RNE; inputs are finite randoms
  return (unsigned short)(u >> 16);
}

// ---- Kernel A: q-path (tiny) + w[bg][c] + zero-init of accumulators -------
__global__ __launch_bounds__(64) void kA(const float* __restrict__ sent,
                                         const float* __restrict__ Wq,
                                         const float* __restrict__ Wk,
                                         const float* __restrict__ g1,
                                         const float* __restrict__ b1,
                                         const float* __restrict__ g2,
                                         float* __restrict__ w_all,
                                         float* __restrict__ sums,
                                         float* __restrict__ outc) {
  int bg = blockIdx.x; int b = bg >> 5; int g = bg & 31;
  int t = threadIdx.x;                       // t = s index (one wave)
  const float* wqrow = Wq + (size_t)(g * 64 + t) * 256;
  const float* se = sent + b * 256;
  float q = 0.f;
  for (int c = 0; c < 256; c += 4) {
    float4 wv = *(const float4*)(wqrow + c); // se[c] is wave-uniform -> s_load
    q += se[c] * wv.x + se[c + 1] * wv.y + se[c + 2] * wv.z + se[c + 3] * wv.w;
  }
  float s = q;
  for (int off = 32; off; off >>= 1) s += __shfl_xor(s, off);
  float mu = s * (1.f / 64.f);
  float d = q - mu;
  float v = d * d;
  for (int off = 32; off; off >>= 1) v += __shfl_xor(v, off);
  float rsq = rsqrtf(v * (1.f / 64.f) + EPS);
  int gs = g * 64 + t;
  float qh = d * rsq * g1[gs] + b1[gs];
  float qg2 = qh * g2[gs];                   // coefficient on K[s,n]
  __shared__ float qs[64];
  qs[t] = qg2;
  __syncthreads();
  float wacc = 0.f;                          // w[c], c = t
  for (int s2 = 0; s2 < 64; s2++)
    wacc += qs[s2] * Wk[(size_t)(g * 64 + s2) * 64 + t];
  w_all[bg * 64 + t] = wacc;
  outc[bg * 64 + t] = 0.f;
  if (t < 2) sums[bg * 2 + t] = 0.f;
}

// ---- Kernel B: per (bg, n-chunk): y[n]=w.x (fp32) + SumK/SumK2 via MFMA ----
__global__ __launch_bounds__(256, 4) void kB(const float* __restrict__ x,
                                             const float* __restrict__ Wk,
                                             const float* __restrict__ w_all,
                                             float* __restrict__ y_all,
                                             float* __restrict__ sums) {
  int bg = blockIdx.y; int b = bg >> 5; int g = bg & 31;
  int n0 = blockIdx.x * CHUNK;
  int t = threadIdx.x;
  int lane = t & 63;
  int wv = t >> 6;

  __shared__ unsigned short xt[64 * 260];   // bf16 tile [c][col], stride 260
  __shared__ float ypart[4 * 256];
  __shared__ float red[8];

  // A-fragments (Wk bf16), 4 s-tiles x 2 c-chunks, lane mapping A[m=l&15][k=(l>>4)*8+j]
  bf16x8 afr[4][2];
  {
    int sA = lane & 15, khi = lane >> 4;
    for (int st = 0; st < 4; st++)
      for (int cc = 0; cc < 2; cc++) {
        short8 tmp;
        const float* wkrow = Wk + (size_t)(g * 64 + st * 16 + sA) * 64 + cc * 32 + khi * 8;
        #pragma unroll
        for (int j = 0; j < 8; j++) tmp[j] = (short)f2bf(wkrow[j]);
        afr[st][cc] = __builtin_bit_cast(bf16x8, tmp);
      }
  }

  // Staging: wave wv owns c = wv (mod 4); lane owns columns lane*4..+3.
  const float* xb = x + ((size_t)(b * 2048 + g * 64)) * NN + n0;
  const float* wp = w_all + bg * 64;
  float y0 = 0, y1 = 0, y2 = 0, y3 = 0;
  #pragma unroll 4
  for (int k = 0; k < 16; k++) {
    int c = wv + 4 * k;
    float4 vx = *(const float4*)(xb + (size_t)c * NN + lane * 4);
    float wc = wp[c];                        // wave-uniform -> scalar load
    y0 += wc * vx.x; y1 += wc * vx.y; y2 += wc * vx.z; y3 += wc * vx.w;
    unsigned p0 = ((unsigned)f2bf(vx.y) << 16) | f2bf(vx.x);
    unsigned p1 = ((unsigned)f2bf(vx.w) << 16) | f2bf(vx.z);
    uint2 pk; pk.x = p0; pk.y = p1;
    *(uint2*)&xt[c * 260 + lane * 4] = pk;
  }
  {
    float4 yp; yp.x = y0; yp.y = y1; yp.z = y2; yp.w = y3;
    *(float4*)&ypart[wv * 256 + lane * 4] = yp;
  }
  __syncthreads();
  // y final (fp32): thread t -> column t
  y_all[(size_t)bg * NN + n0 + t] =
      ypart[t] + ypart[256 + t] + ypart[512 + t] + ypart[768 + t];

  // MFMA: K tiles (never stored), accumulate SumK, SumK^2
  float sk1 = 0.f, sk2 = 0.f;
  int nB = lane & 15;
  int kB_ = (lane >> 4) * 8;
  #pragma unroll
  for (int nt = 0; nt < 4; nt++) {
    int nb = wv * 64 + nt * 16 + nB;
    short8 b0t, b1t;
    #pragma unroll
    for (int j = 0; j < 8; j++) {
      b0t[j] = (short)xt[(kB_ + j) * 260 + nb];
      b1t[j] = (short)xt[(32 + kB_ + j) * 260 + nb];
    }
    bf16x8 bf0 = __builtin_bit_cast(bf16x8, b0t);
    bf16x8 bf1 = __builtin_bit_cast(bf16x8, b1t);
    #pragma unroll
    for (int st = 0; st < 4; st++) {
      f32x4 acc = {0.f, 0.f, 0.f, 0.f};
      acc = __builtin_amdgcn_mfma_f32_16x16x32_bf16(afr[st][0], bf0, acc, 0, 0, 0);
      acc = __builtin_amdgcn_mfma_f32_16x16x32_bf16(afr[st][1], bf1, acc, 0, 0, 0);
      sk1 += acc[0] + acc[1] + acc[2] + acc[3];
      sk2 += acc[0] * acc[0] + acc[1] * acc[1] + acc[2] * acc[2] + acc[3] * acc[3];
    }
  }
  for (int off = 32; off; off >>= 1) {
    sk1 += __shfl_xor(sk1, off);
    sk2 += __shfl_xor(sk2, off);
  }
  if (lane == 0) { red[wv] = sk1; red[4 + wv] = sk2; }
  __syncthreads();
  if (t == 0) {
    atomicAdd(&sums[bg * 2 + 0], red[0] + red[1] + red[2] + red[3]);
    atomicAdd(&sums[bg * 2 + 1], red[4] + red[5] + red[6] + red[7]);
  }
}

// ---- Kernel C: per bg: rs from sums, softmax over 4096 logits -------------
__global__ __launch_bounds__(256) void kC(const float* __restrict__ y_all,
                                          const float* __restrict__ sums,
                                          float* __restrict__ attn) {
  int bg = blockIdx.x; int t = threadIdx.x;
  float s1 = sums[bg * 2], s2 = sums[bg * 2 + 1];
  float mu = s1 * (1.f / 262144.f);
  float var = s2 * (1.f / 262144.f) - mu * mu;
  float rs = rsqrtf(var + EPS);
  const float* y = y_all + (size_t)bg * NN;
  float l[16];
  float m = -1e30f;
  #pragma unroll
  for (int i = 0; i < 16; i++) {
    l[i] = rs * y[t + 256 * i];
    m = fmaxf(m, l[i]);
  }
  __shared__ float red[8];
  for (int off = 32; off; off >>= 1) m = fmaxf(m, __shfl_xor(m, off));
  int wv = t >> 6, lane = t & 63;
  if (lane == 0) red[wv] = m;
  __syncthreads();
  m = fmaxf(fmaxf(red[0], red[1]), fmaxf(red[2], red[3]));
  float sum = 0.f;
  #pragma unroll
  for (int i = 0; i < 16; i++) { l[i] = __expf(l[i] - m); sum += l[i]; }
  for (int off = 32; off; off >>= 1) sum += __shfl_xor(sum, off);
  if (lane == 0) red[4 + wv] = sum;
  __syncthreads();
  float inv = 1.f / (red[4] + red[5] + red[6] + red[7]);
  float* ao = attn + (size_t)bg * NN;
  #pragma unroll
  for (int i = 0; i < 16; i++) ao[t + 256 * i] = l[i] * inv;
}

// ---- Kernel D: out[c] += sum_n attn[n]*x[c,n]  (second x pass, reversed) --
__global__ __launch_bounds__(256) void kD(const float* __restrict__ x,
                                          const float* __restrict__ attn,
                                          float* __restrict__ outc) {
  // Reverse block order: anti-LRU re-read of x against the 256 MiB L3.
  int bg = 255 - blockIdx.y; int b = bg >> 5; int g = bg & 31;
  int n0 = (NCHUNK - 1 - blockIdx.x) * CHUNK;
  int t = threadIdx.x; int lane = t & 63; int wv = t >> 6;
  const float* xb = x + ((size_t)(b * 2048 + g * 64)) * NN + n0;
  float4 a = *(const float4*)(attn + (size_t)bg * NN + n0 + lane * 4);
  float p[16];
  #pragma unroll 4
  for (int k = 0; k < 16; k++) {
    int c = wv + 4 * k;
    float4 vx = *(const float4*)(xb + (size_t)c * NN + lane * 4);
    p[k] = a.x * vx.x + a.y * vx.y + a.z * vx.z + a.w * vx.w;
  }
  #pragma unroll
  for (int k = 0; k < 16; k++) {
    float r = p[k];
    for (int off = 32; off; off >>= 1) r += __shfl_xor(r, off);
    if (lane == 0) atomicAdd(&outc[bg * 64 + wv + 4 * k], r);
  }
}

// ---- Kernel E: result[bg][s] = sum_c outc[bg][c] * Wv[g][s][c] ------------
__global__ __launch_bounds__(64) void kE(const float* __restrict__ outc,
                                         const float* __restrict__ Wv,
                                         float* __restrict__ out) {
  int bg = blockIdx.x; int g = bg & 31;
  int t = threadIdx.x;
  __shared__ float oc[64];
  __shared__ float wvs[64 * 65];
  oc[t] = outc[bg * 64 + t];
  const float* wg = Wv + (size_t)g * 4096;
  for (int i = 0; i < 64; i++) wvs[i * 65 + t] = wg[i * 64 + t];
  __syncthreads();
  float acc = 0.f;
  for (int c = 0; c < 64; c++) acc += wvs[t * 65 + c] * oc[c];
  out[bg * 64 + t] = acc;
}

extern "C" void kernel_launch(void* const* d_in, const int* in_sizes, int n_in,
                              void* d_out, int out_size, void* d_ws, size_t ws_size,
                              hipStream_t stream) {
  const float* x    = (const float*)d_in[0];
  const float* sent = (const float*)d_in[1];
  const float* Wq   = (const float*)d_in[2];
  const float* Wk   = (const float*)d_in[3];
  const float* Wv   = (const float*)d_in[4];
  const float* g1   = (const float*)d_in[5];
  const float* b1   = (const float*)d_in[6];
  const float* g2   = (const float*)d_in[7];
  // d_in[8] = beta2: drops out of softmax (shift-invariance) — unused.
  float* out = (float*)d_out;

  char* ws = (char*)d_ws;
  float* w_all = (float*)(ws);                        // 256*64*4   = 64 KB
  float* sums  = (float*)(ws + 65536);                // 256*2*4    = 2 KB
  float* outc  = (float*)(ws + 67584);                // 256*64*4   = 64 KB
  float* y_all = (float*)(ws + 133120);               // 256*4096*4 = 4 MB
  float* attn  = (float*)(ws + 133120 + 4194304);     // 4 MB

  kA<<<256, 64, 0, stream>>>(sent, Wq, Wk, g1, b1, g2, w_all, sums, outc);
  kB<<<dim3(NCHUNK, 256), 256, 0, stream>>>(x, Wk, w_all, y_all, sums);
  kC<<<256, 256, 0, stream>>>(y_all, sums, attn);
  kD<<<dim3(NCHUNK, 256), 256, 0, stream>>>(x, attn, outc);
  kE<<<256, 64, 0, stream>>>(outc, Wv, out);
}